// Round 7
// baseline (858.391 us; speedup 1.0000x reference)
//
#include <hip/hip_runtime.h>

// GATRotationRegressor — round 16: full split-precision on the R15-validated
// skeleton (minimal diff from R15; no wave-split/barrier/mapping changes).
// R15 (weights hi/lo, fp32 xl, fp32 hreg) measured 0.041 vs 0.039 threshold —
// remaining error = h/yln entering MFMA as plain bf16. This round adds the
// h lo-plane (s_hl) and the third MFMA term everywhere:
//     W*h ~= W_hi*h_hi + W_hi*h_lo + W_lo*h_hi      (drop W_lo*h_lo ~ 2^-18)
// All arithmetic now fp32-grade -> predicted absmax ~1e-3 (threshold 0.039).
// LDS 53568B -> 3 blocks/CU * 2 waves = 6 waves/CU.
// B=16384, J=24, IN=3, H=128, HEADS=4, C=32, OUT=6, L=3.

#define J 24
#define ROWS 48   // 2 batches * 24 joints
#define HB 136    // bf16 LDS row stride in shorts (272 B, 16B-aligned)
#define XLS 132   // fp32 xl/y1 row stride in floats (528 B, 16B-aligned)

typedef __attribute__((ext_vector_type(8))) short short8;
typedef __attribute__((ext_vector_type(4))) float f32x4;

// bf16 weight planes (shorts):
// [0)      Wt hi [l][n][k]  49152      [49152)  Wt lo           49152
// [98304)  w1t hi [m][k]     8192      [106496) w1t lo           8192
// [114688) wa hi [l][j][k]   6144      [120832) wa lo            6144
// [126976) w2t hi [o][m]     1024      [128000) w2t lo           1024
__device__ unsigned short g_wt[129024];

// packed incidence: deg | inc0<<3 | inc1<<8 | inc2<<13 | inc3<<18 | inc4<<23
#define PK5(d,a,b,c,e,f) ((unsigned)(d)|((unsigned)(a)<<3)|((unsigned)(b)<<8)|((unsigned)(c)<<13)|((unsigned)(e)<<18)|((unsigned)(f)<<23))
__constant__ unsigned c_pack[J] = {
  PK5(4,1,2,3,0,0),  PK5(3,0,4,1,0,0),  PK5(3,0,5,2,0,0),  PK5(3,0,6,3,0,0),
  PK5(3,1,7,4,0,0),  PK5(3,2,8,5,0,0),  PK5(3,3,9,6,0,0),  PK5(3,4,10,7,0,0),
  PK5(3,5,11,8,0,0), PK5(5,6,12,13,14,9),PK5(2,7,10,0,0,0), PK5(2,8,11,0,0,0),
  PK5(3,9,15,12,0,0),PK5(3,9,16,13,0,0),PK5(3,9,17,14,0,0),PK5(2,12,15,0,0,0),
  PK5(3,13,18,16,0,0),PK5(3,14,19,17,0,0),PK5(3,16,20,18,0,0),PK5(3,17,21,19,0,0),
  PK5(3,18,22,20,0,0),PK5(3,19,23,21,0,0),PK5(2,20,22,0,0,0),PK5(2,21,23,0,0,0)
};

__device__ __forceinline__ unsigned short f2bf(float f) {
  unsigned u = __builtin_bit_cast(unsigned, f);
  u = (u + 0x7FFFu + ((u >> 16) & 1u)) >> 16;   // RNE
  return (unsigned short)u;
}
__device__ __forceinline__ float bf2f(unsigned short u) {
  return __builtin_bit_cast(float, (unsigned)u << 16);
}
// pack two values' hi-bf16s and lo-bf16s (lo = RNE(v - hi))
__device__ __forceinline__ void pk_hl(float a, float b, unsigned &ph, unsigned &pl) {
  const unsigned short ha = f2bf(a), hb = f2bf(b);
  const unsigned short la = f2bf(a - bf2f(ha)), lb = f2bf(b - bf2f(hb));
  ph = (unsigned)ha | ((unsigned)hb << 16);
  pl = (unsigned)la | ((unsigned)lb << 16);
}

__global__ __launch_bounds__(256) void prep_weights(
    const float* __restrict__ gat_w, const float* __restrict__ att_s,
    const float* __restrict__ att_d, const float* __restrict__ w1,
    const float* __restrict__ w2)
{
  const int idx = blockIdx.x * 256 + threadIdx.x;
  float v; int hi_off, lo_off;
  if (idx < 49152) {
    const int l = idx >> 14, rem = idx & 16383, n = rem >> 7, k = rem & 127;
    v = gat_w[l*16384 + k*128 + n];
    hi_off = idx; lo_off = 49152 + idx;
  } else if (idx < 57344) {
    const int i2 = idx - 49152, m = i2 >> 7, k = i2 & 127;
    v = w1[k*64 + m];
    hi_off = 98304 + i2; lo_off = 106496 + i2;
  } else if (idx < 63488) {
    const int i2 = idx - 57344;
    const int l = i2 >> 11, r = i2 & 2047, j = r >> 7, k = r & 127;
    v = 0.f;
    if (j < 8) {
      const int sd = j >> 2, hhh = j & 3;
      const float* av = (sd ? att_d : att_s) + (l*4 + hhh)*32;
      const float* wp = gat_w + l*16384 + k*128 + hhh*32;
#pragma unroll 8
      for (int c = 0; c < 32; ++c) v += wp[c] * av[c];
    }
    hi_off = 114688 + i2; lo_off = 120832 + i2;
  } else if (idx < 64512) {
    const int i2 = idx - 63488, o = i2 >> 6, m = i2 & 63;
    v = (o < 6) ? w2[m*6 + o] : 0.f;
    hi_off = 126976 + i2; lo_off = 128000 + i2;
  } else return;
  const unsigned short h = f2bf(v);
  g_wt[hi_off] = h;
  g_wt[lo_off] = f2bf(v - bf2f(h));
}

__global__ __launch_bounds__(128) void gat_fused(
    const float* __restrict__ x,     const float* __restrict__ in_w,  const float* __restrict__ in_b,
    const float* __restrict__ res_w, const float* __restrict__ res_b, const float* __restrict__ pos,
    const float* __restrict__ gat_b, const float* __restrict__ ln_g,  const float* __restrict__ ln_b,
    const float* __restrict__ b1,    const float* __restrict__ lng2,  const float* __restrict__ lnb2,
    const float* __restrict__ b2,    float* __restrict__ out)
{
  __shared__ __align__(16) unsigned short s_hb[ROWS*HB];   // h hi plane (later yln hi)
  __shared__ __align__(16) unsigned short s_hl[ROWS*HB];   // h lo plane (later yln lo)
  __shared__ __align__(16) float          s_xl[ROWS*XLS];  // xl fp32; later y1 fp32
  __shared__ float s_x[144];        // 2 batches * 24 joints * 3
  __shared__ float s_asd[ROWS*8];   // cols 0..3 a_s, 4..7 a_d

  const int tid = threadIdx.x;
  const long blk = blockIdx.x;      // covers batches 2*blk, 2*blk+1
  const int l16 = tid & 15, q = (tid >> 4) & 3;  // wave-0 MFMA coords
  const int c8 = tid & 7, cb = c8*16, hh = c8 >> 1;
  const int g16 = tid >> 3;                      // 0..15 (row-group id)

  float hreg[3][16];  // fp32 h master: rows g16+16*i, chans [cb,cb+16)

  // ---- P0: stage x for both batches ----
  {
    const float* xb = x + blk*144;
    s_x[tid] = xb[tid];
    if (tid < 16) s_x[128 + tid] = xb[128 + tid];
  }
  __syncthreads();

  // ---- P1: input projection -> hreg fp32 + s_hb/s_hl planes; both waves ----
#pragma unroll
  for (int i = 0; i < 3; ++i) {
    const int r = g16 + 16*i;
    const int bp = (r >= 24) ? 1 : 0;
    const int j = r - 24*bp;
    const float x0 = s_x[bp*72 + j*3], x1 = s_x[bp*72 + j*3 + 1], x2 = s_x[bp*72 + j*3 + 2];
    float v[16];
#pragma unroll
    for (int c4 = 0; c4 < 4; ++c4) {
      const float4 w0 = *(const float4*)&in_w[      cb + c4*4];
      const float4 w1v= *(const float4*)&in_w[128 + cb + c4*4];
      const float4 w2v= *(const float4*)&in_w[256 + cb + c4*4];
      const float4 bb = *(const float4*)&in_b[      cb + c4*4];
      const float4 pp = *(const float4*)&pos[j*128 + cb + c4*4];
      v[c4*4+0] = x0*w0.x + x1*w1v.x + x2*w2v.x + bb.x + pp.x;
      v[c4*4+1] = x0*w0.y + x1*w1v.y + x2*w2v.y + bb.y + pp.y;
      v[c4*4+2] = x0*w0.z + x1*w1v.z + x2*w2v.z + bb.z + pp.z;
      v[c4*4+3] = x0*w0.w + x1*w1v.w + x2*w2v.w + bb.w + pp.w;
    }
#pragma unroll
    for (int c = 0; c < 16; ++c) hreg[i][c] = v[c];
    uint4 ph0, ph1, pl0, pl1;
    pk_hl(v[0],v[1],ph0.x,pl0.x);   pk_hl(v[2],v[3],ph0.y,pl0.y);
    pk_hl(v[4],v[5],ph0.z,pl0.z);   pk_hl(v[6],v[7],ph0.w,pl0.w);
    pk_hl(v[8],v[9],ph1.x,pl1.x);   pk_hl(v[10],v[11],ph1.y,pl1.y);
    pk_hl(v[12],v[13],ph1.z,pl1.z); pk_hl(v[14],v[15],ph1.w,pl1.w);
    *(uint4*)&s_hb[r*HB + cb]     = ph0;
    *(uint4*)&s_hb[r*HB + cb + 8] = ph1;
    *(uint4*)&s_hl[r*HB + cb]     = pl0;
    *(uint4*)&s_hl[r*HB + cb + 8] = pl1;
  }
  __syncthreads();

  // ---- GAT layers ----
#pragma unroll 1
  for (int l = 0; l < 3; ++l) {
    // === L1 + logits: wave 0 only (R15 structure), 3-term split MFMA ===
    if (tid < 64) {
      short8 af[3][4], afl[3][4];
#pragma unroll
      for (int t = 0; t < 3; ++t)
#pragma unroll
        for (int ks = 0; ks < 4; ++ks) {
          af [t][ks] = *(const short8*)&s_hb[(t*16 + l16)*HB + ks*32 + q*8];
          afl[t][ks] = *(const short8*)&s_hl[(t*16 + l16)*HB + ks*32 + q*8];
        }

      const unsigned short* Wh  = &g_wt[l*16384];
      const unsigned short* Wlo = &g_wt[49152 + l*16384];
#pragma unroll 1
      for (int nt = 0; nt < 8; ++nt) {
        f32x4 acc[3] = { {0,0,0,0}, {0,0,0,0}, {0,0,0,0} };
#pragma unroll
        for (int ks = 0; ks < 4; ++ks) {
          const short8 whi = *(const short8*)&Wh [(nt*16 + l16)*128 + ks*32 + q*8];
          const short8 wlo = *(const short8*)&Wlo[(nt*16 + l16)*128 + ks*32 + q*8];
#pragma unroll
          for (int t = 0; t < 3; ++t) {
            acc[t] = __builtin_amdgcn_mfma_f32_16x16x32_bf16(whi, af [t][ks], acc[t], 0, 0, 0);
            acc[t] = __builtin_amdgcn_mfma_f32_16x16x32_bf16(whi, afl[t][ks], acc[t], 0, 0, 0);
            acc[t] = __builtin_amdgcn_mfma_f32_16x16x32_bf16(wlo, af [t][ks], acc[t], 0, 0, 0);
          }
        }
#pragma unroll
        for (int t = 0; t < 3; ++t) {
          float4 w;
          w.x = acc[t][0]; w.y = acc[t][1]; w.z = acc[t][2]; w.w = acc[t][3];
          *(float4*)&s_xl[(t*16 + l16)*XLS + nt*16 + q*4] = w;   // fp32 xl
        }
      }
      // logits: D[m=wa-col][n=h-row]; q<2 holds cols 0..7
      const unsigned short* Wah = &g_wt[114688 + l*2048];
      const unsigned short* Wal = &g_wt[120832 + l*2048];
      f32x4 la[3] = { {0,0,0,0}, {0,0,0,0}, {0,0,0,0} };
#pragma unroll
      for (int ks = 0; ks < 4; ++ks) {
        const short8 bah = *(const short8*)&Wah[l16*128 + ks*32 + q*8];
        const short8 bal = *(const short8*)&Wal[l16*128 + ks*32 + q*8];
#pragma unroll
        for (int t = 0; t < 3; ++t) {
          la[t] = __builtin_amdgcn_mfma_f32_16x16x32_bf16(bah, af [t][ks], la[t], 0, 0, 0);
          la[t] = __builtin_amdgcn_mfma_f32_16x16x32_bf16(bah, afl[t][ks], la[t], 0, 0, 0);
          la[t] = __builtin_amdgcn_mfma_f32_16x16x32_bf16(bal, af [t][ks], la[t], 0, 0, 0);
        }
      }
      if (q < 2) {
#pragma unroll
        for (int t = 0; t < 3; ++t) {
          float4 w; w.x = la[t][0]; w.y = la[t][1]; w.z = la[t][2]; w.w = la[t][3];
          *(float4*)&s_asd[(t*16 + l16)*8 + q*4] = w;
        }
      }
    }
    __syncthreads();

    // === L3: BOTH waves; unrolled (hreg static); fp32 aggregate + residual ===
#pragma unroll
    for (int i = 0; i < 3; ++i) {
      const int r = g16 + 16*i;
      const int bp = (r >= 24) ? 1 : 0;
      const int base = 24*bp, j = r - base;
      const unsigned pkw = c_pack[j];
      const int dg = pkw & 7;
      const unsigned pp = pkw >> 3;

      // softmax over incoming edges for (row r, head hh)
      const float ad = s_asd[r*8 + 4 + hh];
      float al[5];
      float mx = -1e30f;
#pragma unroll
      for (int e = 0; e < 5; ++e) if (e < dg) {
        const int src = (pp >> (5*e)) & 31;
        float ee = s_asd[(base + src)*8 + hh] + ad;
        ee = (ee >= 0.f) ? ee : 0.2f*ee;
        al[e] = ee;
        mx = fmaxf(mx, ee);
      }
      float den = 0.f;
#pragma unroll
      for (int e = 0; e < 5; ++e) if (e < dg) { al[e] = __expf(al[e]-mx); den += al[e]; }
      const float inv = 1.f/den;

      float ov[16];
#pragma unroll
      for (int c4 = 0; c4 < 4; ++c4) {
        const float4 gb4 = *(const float4*)&gat_b[l*128 + cb + c4*4];
        ov[c4*4+0]=gb4.x; ov[c4*4+1]=gb4.y; ov[c4*4+2]=gb4.z; ov[c4*4+3]=gb4.w;
      }
#pragma unroll
      for (int e = 0; e < 5; ++e) if (e < dg) {
        const float a = al[e]*inv;
        const int src = (pp >> (5*e)) & 31;
        const float* xp = &s_xl[(base + src)*XLS + cb];
#pragma unroll
        for (int c4 = 0; c4 < 4; ++c4) {
          const float4 x4 = *(const float4*)&xp[c4*4];
          ov[c4*4+0] += a * x4.x;
          ov[c4*4+1] += a * x4.y;
          ov[c4*4+2] += a * x4.z;
          ov[c4*4+3] += a * x4.w;
        }
      }
      float s = 0.f, s2 = 0.f;
#pragma unroll
      for (int c = 0; c < 16; ++c) {
        float v = ov[c];
        v = (v > 0.f) ? v : (__expf(v) - 1.f);   // elu
        ov[c] = v;
        s += v; s2 += v*v;
      }
#pragma unroll
      for (int off = 1; off < 8; off <<= 1) {
        s  += __shfl_xor(s,  off, 64);
        s2 += __shfl_xor(s2, off, 64);
      }
      const float mean = s * (1.f/128.f);
      const float rstd = rsqrtf(s2 * (1.f/128.f) - mean*mean + 1e-5f);

#pragma unroll
      for (int c4 = 0; c4 < 4; ++c4) {
        const float4 lg4 = *(const float4*)&ln_g[l*128 + cb + c4*4];
        const float4 lb4 = *(const float4*)&ln_b[l*128 + cb + c4*4];
        const float lgv[4] = {lg4.x, lg4.y, lg4.z, lg4.w};
        const float lbv[4] = {lb4.x, lb4.y, lb4.z, lb4.w};
#pragma unroll
        for (int cc = 0; cc < 4; ++cc) {
          const int c = c4*4 + cc;
          float v = (ov[c]-mean)*rstd*lgv[cc] + lbv[cc];
          if (l > 0) v += hreg[i][c];           // fp32 residual
          ov[c] = v;
        }
      }
      if (l == 2) {   // fold h += res into last layer's apply
        const float x0 = s_x[bp*72 + j*3], x1 = s_x[bp*72 + j*3 + 1], x2 = s_x[bp*72 + j*3 + 2];
#pragma unroll
        for (int c4 = 0; c4 < 4; ++c4) {
          const float4 rw0 = *(const float4*)&res_w[      cb + c4*4];
          const float4 rw1 = *(const float4*)&res_w[128 + cb + c4*4];
          const float4 rw2 = *(const float4*)&res_w[256 + cb + c4*4];
          const float4 rb4 = *(const float4*)&res_b[      cb + c4*4];
          ov[c4*4+0] += x0*rw0.x + x1*rw1.x + x2*rw2.x + rb4.x;
          ov[c4*4+1] += x0*rw0.y + x1*rw1.y + x2*rw2.y + rb4.y;
          ov[c4*4+2] += x0*rw0.z + x1*rw1.z + x2*rw2.z + rb4.z;
          ov[c4*4+3] += x0*rw0.w + x1*rw1.w + x2*rw2.w + rb4.w;
        }
      }
#pragma unroll
      for (int c = 0; c < 16; ++c) hreg[i][c] = ov[c];  // fp32 master update
      uint4 ph0, ph1, pl0, pl1;
      pk_hl(ov[0],ov[1],ph0.x,pl0.x);   pk_hl(ov[2],ov[3],ph0.y,pl0.y);
      pk_hl(ov[4],ov[5],ph0.z,pl0.z);   pk_hl(ov[6],ov[7],ph0.w,pl0.w);
      pk_hl(ov[8],ov[9],ph1.x,pl1.x);   pk_hl(ov[10],ov[11],ph1.y,pl1.y);
      pk_hl(ov[12],ov[13],ph1.z,pl1.z); pk_hl(ov[14],ov[15],ph1.w,pl1.w);
      *(uint4*)&s_hb[r*HB + cb]     = ph0;
      *(uint4*)&s_hb[r*HB + cb + 8] = ph1;
      *(uint4*)&s_hl[r*HB + cb]     = pl0;
      *(uint4*)&s_hl[r*HB + cb + 8] = pl1;
    }
    __syncthreads();
  }

  // ---- F1: y1 = relu(h @ w1t + b1); wave 0, 4 nt, 3-term; fp32 -> s_xl ----
  if (tid < 64) {
    const unsigned short* W1h = &g_wt[98304];
    const unsigned short* W1l = &g_wt[106496];
    short8 af[3][4], afl[3][4];
#pragma unroll
    for (int t = 0; t < 3; ++t)
#pragma unroll
      for (int ks = 0; ks < 4; ++ks) {
        af [t][ks] = *(const short8*)&s_hb[(t*16 + l16)*HB + ks*32 + q*8];
        afl[t][ks] = *(const short8*)&s_hl[(t*16 + l16)*HB + ks*32 + q*8];
      }
#pragma unroll 1
    for (int nt = 0; nt < 4; ++nt) {
      const float4 b1v = *(const float4*)&b1[nt*16 + q*4];
      f32x4 acc[3];
#pragma unroll
      for (int t = 0; t < 3; ++t) { acc[t][0]=b1v.x; acc[t][1]=b1v.y; acc[t][2]=b1v.z; acc[t][3]=b1v.w; }
#pragma unroll
      for (int ks = 0; ks < 4; ++ks) {
        const short8 whi = *(const short8*)&W1h[(nt*16 + l16)*128 + ks*32 + q*8];
        const short8 wlo = *(const short8*)&W1l[(nt*16 + l16)*128 + ks*32 + q*8];
#pragma unroll
        for (int t = 0; t < 3; ++t) {
          acc[t] = __builtin_amdgcn_mfma_f32_16x16x32_bf16(whi, af [t][ks], acc[t], 0, 0, 0);
          acc[t] = __builtin_amdgcn_mfma_f32_16x16x32_bf16(whi, afl[t][ks], acc[t], 0, 0, 0);
          acc[t] = __builtin_amdgcn_mfma_f32_16x16x32_bf16(wlo, af [t][ks], acc[t], 0, 0, 0);
        }
      }
#pragma unroll
      for (int t = 0; t < 3; ++t) {
        float4 w;
        w.x = fmaxf(acc[t][0], 0.f); w.y = fmaxf(acc[t][1], 0.f);
        w.z = fmaxf(acc[t][2], 0.f); w.w = fmaxf(acc[t][3], 0.f);
        *(float4*)&s_xl[(t*16 + l16)*XLS + nt*16 + q*4] = w;
      }
    }
  }
  __syncthreads();

  // ---- F2: LN(64) on fp32 y1; yln hi/lo -> s_hb/s_hl; 96 items ----
  if (tid < 96) {
    const int row = tid >> 1, half = tid & 1;
    const float* yr = &s_xl[row*XLS + half*32];
    float yv[32];
    float s = 0.f, s2 = 0.f;
#pragma unroll
    for (int c4 = 0; c4 < 8; ++c4) {
      const float4 v4 = *(const float4*)&yr[c4*4];
      yv[c4*4+0]=v4.x; yv[c4*4+1]=v4.y; yv[c4*4+2]=v4.z; yv[c4*4+3]=v4.w;
      s += v4.x+v4.y+v4.z+v4.w;
      s2 += v4.x*v4.x + v4.y*v4.y + v4.z*v4.z + v4.w*v4.w;
    }
    s  += __shfl_xor(s,  1, 64);
    s2 += __shfl_xor(s2, 1, 64);
    const float mean = s * (1.f/64.f);
    const float rstd = rsqrtf(s2 * (1.f/64.f) - mean*mean + 1e-5f);
    float yl[32];
#pragma unroll
    for (int c = 0; c < 32; ++c) {
      const int m = half*32 + c;
      yl[c] = (yv[c]-mean)*rstd*lng2[m] + lnb2[m];
    }
    uint4 phA, phB, plA, plB;
    pk_hl(yl[0],yl[1],phA.x,plA.x);   pk_hl(yl[2],yl[3],phA.y,plA.y);
    pk_hl(yl[4],yl[5],phA.z,plA.z);   pk_hl(yl[6],yl[7],phA.w,plA.w);
    pk_hl(yl[8],yl[9],phB.x,plB.x);   pk_hl(yl[10],yl[11],phB.y,plB.y);
    pk_hl(yl[12],yl[13],phB.z,plB.z); pk_hl(yl[14],yl[15],phB.w,plB.w);
    *(uint4*)&s_hb[row*HB + half*32]     = phA;
    *(uint4*)&s_hb[row*HB + half*32 + 8] = phB;
    *(uint4*)&s_hl[row*HB + half*32]     = plA;
    *(uint4*)&s_hl[row*HB + half*32 + 8] = plB;
    pk_hl(yl[16],yl[17],phA.x,plA.x); pk_hl(yl[18],yl[19],phA.y,plA.y);
    pk_hl(yl[20],yl[21],phA.z,plA.z); pk_hl(yl[22],yl[23],phA.w,plA.w);
    pk_hl(yl[24],yl[25],phB.x,plB.x); pk_hl(yl[26],yl[27],phB.y,plB.y);
    pk_hl(yl[28],yl[29],phB.z,plB.z); pk_hl(yl[30],yl[31],phB.w,plB.w);
    *(uint4*)&s_hb[row*HB + half*32 + 16] = phA;
    *(uint4*)&s_hb[row*HB + half*32 + 24] = phB;
    *(uint4*)&s_hl[row*HB + half*32 + 16] = plA;
    *(uint4*)&s_hl[row*HB + half*32 + 24] = plB;
  }
  __syncthreads();

  // ---- F3: out = yln @ w2t + b2; wave 0; 3-term ----
  if (tid < 64) {
    const unsigned short* W2h = &g_wt[126976];
    const unsigned short* W2l = &g_wt[128000];
    const short8 b0h = *(const short8*)&W2h[l16*64 + q*8];
    const short8 b0l = *(const short8*)&W2l[l16*64 + q*8];
    const short8 b1h = *(const short8*)&W2h[l16*64 + 32 + q*8];
    const short8 b1l = *(const short8*)&W2l[l16*64 + 32 + q*8];
#pragma unroll 1
    for (int t = 0; t < 3; ++t) {
      f32x4 acc = {0,0,0,0};
      const short8 a0  = *(const short8*)&s_hb[(t*16 + l16)*HB + q*8];
      const short8 a0l = *(const short8*)&s_hl[(t*16 + l16)*HB + q*8];
      acc = __builtin_amdgcn_mfma_f32_16x16x32_bf16(b0h, a0,  acc, 0, 0, 0);
      acc = __builtin_amdgcn_mfma_f32_16x16x32_bf16(b0h, a0l, acc, 0, 0, 0);
      acc = __builtin_amdgcn_mfma_f32_16x16x32_bf16(b0l, a0,  acc, 0, 0, 0);
      const short8 a1  = *(const short8*)&s_hb[(t*16 + l16)*HB + 32 + q*8];
      const short8 a1l = *(const short8*)&s_hl[(t*16 + l16)*HB + 32 + q*8];
      acc = __builtin_amdgcn_mfma_f32_16x16x32_bf16(b1h, a1,  acc, 0, 0, 0);
      acc = __builtin_amdgcn_mfma_f32_16x16x32_bf16(b1h, a1l, acc, 0, 0, 0);
      acc = __builtin_amdgcn_mfma_f32_16x16x32_bf16(b1l, a1,  acc, 0, 0, 0);
      const int row = t*16 + l16;
      const int bp = (row >= 24) ? 1 : 0;
      const int jj = row - 24*bp;
      float* op = out + (blk*2 + bp)*144 + jj*6;
      if (q == 0) {
        float4 w;
        w.x = acc[0] + b2[0]; w.y = acc[1] + b2[1];
        w.z = acc[2] + b2[2]; w.w = acc[3] + b2[3];
        *(float4*)op = w;
      } else if (q == 1) {
        float2 w;
        w.x = acc[0] + b2[4]; w.y = acc[1] + b2[5];
        *(float2*)(op + 4) = w;
      }
    }
  }
}

extern "C" void kernel_launch(void* const* d_in, const int* in_sizes, int n_in,
                              void* d_out, int out_size, void* d_ws, size_t ws_size,
                              hipStream_t stream) {
  (void)n_in; (void)out_size; (void)d_ws; (void)ws_size;
  const float* x     = (const float*)d_in[0];
  const float* in_w  = (const float*)d_in[1];
  const float* in_b  = (const float*)d_in[2];
  const float* res_w = (const float*)d_in[3];
  const float* res_b = (const float*)d_in[4];
  const float* pos   = (const float*)d_in[5];
  const float* gat_w = (const float*)d_in[6];
  const float* att_s = (const float*)d_in[7];
  const float* att_d = (const float*)d_in[8];
  const float* gat_b = (const float*)d_in[9];
  const float* ln_g  = (const float*)d_in[10];
  const float* ln_b  = (const float*)d_in[11];
  const float* w1    = (const float*)d_in[12];
  const float* b1    = (const float*)d_in[13];
  const float* lng2  = (const float*)d_in[14];
  const float* lnb2  = (const float*)d_in[15];
  const float* w2    = (const float*)d_in[16];
  const float* b2    = (const float*)d_in[17];
  float* out = (float*)d_out;

  const int B = in_sizes[0] / (J*3);
  hipLaunchKernelGGL(prep_weights, dim3((64512 + 255)/256), dim3(256), 0, stream,
                     gat_w, att_s, att_d, w1, w2);
  hipLaunchKernelGGL(gat_fused, dim3(B/2), dim3(128), 0, stream,
                     x, in_w, in_b, res_w, res_b, pos, gat_b, ln_g, ln_b,
                     b1, lng2, lnb2, b2, out);
}